// Round 1
// baseline (1211.031 us; speedup 1.0000x reference)
//
#include <hip/hip_runtime.h>

// ---------------------------------------------------------------------------
// GNN: 3x GraphConv(H=64) + global_mean_pool + Linear(64->2)
// N=100000 nodes, E=1200000 edges, G=256 graphs, C_IN=1, C_OUT=2
//
// Structure exploited:
//  - layer1: C_IN=1 -> scalar edge aggregation
//  - layer3 + pool + head are linear -> fold W3_rel@W_lin / W3_root@W_lin into
//    per-node 4-vector z; never materialize h3 or even h2 to global.
// ---------------------------------------------------------------------------

static __device__ __forceinline__ float4 ld4(const float* p) {
    return *reinterpret_cast<const float4*>(p);
}

// Small precompute: Mrel = W3_rel @ W_lin [64x2], Mroot = W3_root @ W_lin [64x2],
// b3W[c] = b3 @ W_lin (b_lin added in final kernel). Also transpose W2 weights.
__global__ void k_small(const float* __restrict__ W3_rel, const float* __restrict__ b3,
                        const float* __restrict__ W3_root, const float* __restrict__ W_lin,
                        const float* __restrict__ W2_rel, const float* __restrict__ W2_root,
                        float* __restrict__ Mrel, float* __restrict__ Mroot,
                        float* __restrict__ b3W,
                        float* __restrict__ W2relT, float* __restrict__ W2rootT)
{
    int t = threadIdx.x; // 256 threads
    // transpose W2 (row-major [k][j] -> [j][k]) so k_node2 can read b128 along k
    for (int i = t; i < 4096; i += 256) {
        int k = i >> 6, j = i & 63;
        W2relT[j * 64 + k]  = W2_rel[i];
        W2rootT[j * 64 + k] = W2_root[i];
    }
    if (t < 128) {
        int i = t >> 1, c = t & 1;
        float sr = 0.f, so = 0.f;
        for (int k = 0; k < 64; ++k) {
            float wl = W_lin[k * 2 + c];
            sr += W3_rel[i * 64 + k] * wl;
            so += W3_root[i * 64 + k] * wl;
        }
        Mrel[t]  = sr;
        Mroot[t] = so;
    }
    if (t < 2) {
        float s = 0.f;
        for (int k = 0; k < 64; ++k) s += b3[k] * W_lin[k * 2 + t];
        b3W[t] = s;
    }
}

// Layer-1 edge pass: agg1[dst] += ew * x[src]  (scalar, C_IN = 1)
__global__ __launch_bounds__(256) void k_edge1(const int* __restrict__ src,
                                               const int* __restrict__ dst,
                                               const float* __restrict__ ew,
                                               const float* __restrict__ x,
                                               float* __restrict__ agg1, int E)
{
    int e = blockIdx.x * blockDim.x + threadIdx.x;
    if (e < E) atomicAdd(&agg1[dst[e]], ew[e] * x[src[e]]);
}

// Layer-1 node pass: h1[n][j] = relu(agg1[n]*W1_rel[j] + x[n]*W1_root[j] + b1[j])
__global__ __launch_bounds__(256) void k_node1(const float* __restrict__ x,
                                               const float* __restrict__ agg1,
                                               const float* __restrict__ W1_rel,
                                               const float* __restrict__ b1,
                                               const float* __restrict__ W1_root,
                                               float* __restrict__ h1, int N)
{
    __shared__ float wr[64], bb[64], wo[64];
    if (threadIdx.x < 64) {
        wr[threadIdx.x] = W1_rel[threadIdx.x];
        bb[threadIdx.x] = b1[threadIdx.x];
        wo[threadIdx.x] = W1_root[threadIdx.x];
    }
    __syncthreads();
    int t = blockIdx.x * blockDim.x + threadIdx.x;
    if (t < N * 16) {
        int n = t >> 4, q = (t & 15) << 2;
        float a = agg1[n], xv = x[n];
        float4 o;
        o.x = fmaxf(a * wr[q + 0] + xv * wo[q + 0] + bb[q + 0], 0.f);
        o.y = fmaxf(a * wr[q + 1] + xv * wo[q + 1] + bb[q + 1], 0.f);
        o.z = fmaxf(a * wr[q + 2] + xv * wo[q + 2] + bb[q + 2], 0.f);
        o.w = fmaxf(a * wr[q + 3] + xv * wo[q + 3] + bb[q + 3], 0.f);
        *reinterpret_cast<float4*>(&h1[(size_t)n * 64 + q]) = o;
    }
}

// Layer-2 edge pass (the heavy one): agg2[dst][:] += ew * h1[src][:]
// 16 threads per edge, each thread handles a float4 chunk of the 64-channel row.
__global__ __launch_bounds__(256) void k_edge2(const int* __restrict__ src,
                                               const int* __restrict__ dst,
                                               const float* __restrict__ ew,
                                               const float* __restrict__ h1,
                                               float* __restrict__ agg2, int E)
{
    int tid = blockIdx.x * blockDim.x + threadIdx.x;
    int e = tid >> 4;
    int q = (tid & 15) << 2;
    if (e < E) {
        int s = src[e], d = dst[e];
        float w = ew[e];
        float4 v = ld4(&h1[(size_t)s * 64 + q]);
        float* p = &agg2[(size_t)d * 64 + q];
        atomicAdd(p + 0, v.x * w);
        atomicAdd(p + 1, v.y * w);
        atomicAdd(p + 2, v.z * w);
        atomicAdd(p + 3, v.w * w);
    }
}

// Layer-2 node pass fused with layer-3 fold:
//   h2 = relu(agg2 @ W2_rel + h1 @ W2_root + b2)       (kept in registers)
//   z[n][0:2] = h2 @ Mrel ; z[n][2:4] = h2 @ Mroot     (only thing written)
// Tile: 64 nodes x 64 cols per block (256 thr), 4x4 outputs per thread.
__global__ __launch_bounds__(256) void k_node2(const float* __restrict__ agg2,
                                               const float* __restrict__ h1g,
                                               const float* __restrict__ W2relT,
                                               const float* __restrict__ b2,
                                               const float* __restrict__ W2rootT,
                                               const float* __restrict__ Mrel,
                                               const float* __restrict__ Mroot,
                                               float* __restrict__ z, int N)
{
    __shared__ float A2[64][68];  // +4 pad keeps 16B align, breaks bank aliasing
    __shared__ float H1[64][68];
    __shared__ float BB[64];
    __shared__ float MC[64][4];

    const int t = threadIdx.x;
    if (t < 64) BB[t] = b2[t];
    if (t < 128) {
        int j = t >> 1, c = t & 1;
        MC[j][c]     = Mrel[t];
        MC[j][c + 2] = Mroot[t];
    }

    const int n0 = blockIdx.x * 64;
    for (int i = t; i < 1024; i += 256) {
        int r = i >> 4, q = (i & 15) << 2;
        int n = n0 + r;
        float4 a, h;
        if (n < N) {
            a = ld4(&agg2[(size_t)n * 64 + q]);
            h = ld4(&h1g[(size_t)n * 64 + q]);
        } else {
            a = make_float4(0.f, 0.f, 0.f, 0.f);
            h = a;
        }
        *reinterpret_cast<float4*>(&A2[r][q]) = a;
        *reinterpret_cast<float4*>(&H1[r][q]) = h;
    }
    __syncthreads();

    const int ng = t >> 4, jg = t & 15;
    const int rn = ng << 2;   // 4 node rows
    const int jb = jg << 2;   // 4 output cols

    float acc[4][4];
#pragma unroll
    for (int i = 0; i < 4; ++i)
#pragma unroll
        for (int j = 0; j < 4; ++j) acc[i][j] = 0.f;

    for (int k = 0; k < 64; k += 4) {
        float4 av[4], hv[4], wv[4], ov[4];
#pragma unroll
        for (int i = 0; i < 4; ++i) {
            av[i] = *reinterpret_cast<float4*>(&A2[rn + i][k]);
            hv[i] = *reinterpret_cast<float4*>(&H1[rn + i][k]);
        }
#pragma unroll
        for (int j = 0; j < 4; ++j) {
            wv[j] = ld4(&W2relT[(jb + j) * 64 + k]);   // L1-resident (32KB shared by all blocks)
            ov[j] = ld4(&W2rootT[(jb + j) * 64 + k]);
        }
#pragma unroll
        for (int i = 0; i < 4; ++i)
#pragma unroll
            for (int j = 0; j < 4; ++j) {
                acc[i][j] += av[i].x * wv[j].x + av[i].y * wv[j].y +
                             av[i].z * wv[j].z + av[i].w * wv[j].w +
                             hv[i].x * ov[j].x + hv[i].y * ov[j].y +
                             hv[i].z * ov[j].z + hv[i].w * ov[j].w;
            }
    }

    // epilogue: bias + relu, fold to z (4 floats per node), reduce over 16 jg lanes
    float4 p[4];
#pragma unroll
    for (int i = 0; i < 4; ++i) {
        float z0 = 0.f, z1 = 0.f, z2 = 0.f, z3 = 0.f;
#pragma unroll
        for (int j = 0; j < 4; ++j) {
            float h2 = fmaxf(acc[i][j] + BB[jb + j], 0.f);
            z0 += h2 * MC[jb + j][0];
            z1 += h2 * MC[jb + j][1];
            z2 += h2 * MC[jb + j][2];
            z3 += h2 * MC[jb + j][3];
        }
        p[i] = make_float4(z0, z1, z2, z3);
    }
#pragma unroll
    for (int m = 1; m < 16; m <<= 1) {
#pragma unroll
        for (int i = 0; i < 4; ++i) {
            p[i].x += __shfl_xor(p[i].x, m);
            p[i].y += __shfl_xor(p[i].y, m);
            p[i].z += __shfl_xor(p[i].z, m);
            p[i].w += __shfl_xor(p[i].w, m);
        }
    }
    if (jg == 0) {
#pragma unroll
        for (int i = 0; i < 4; ++i) {
            int n = n0 + rn + i;
            if (n < N) *reinterpret_cast<float4*>(&z[(size_t)n * 4]) = p[i];
        }
    }
}

// Pool: per-graph accumulation of edge-path (ew * z[src].xy into batch[dst])
// and node-path (z[n].zw into batch[n]) plus counts. LDS-buffered per block.
__global__ __launch_bounds__(256) void k_pool(const int* __restrict__ src,
                                              const int* __restrict__ dst,
                                              const float* __restrict__ ew,
                                              const int* __restrict__ batch,
                                              const float* __restrict__ z,
                                              float* __restrict__ gacc,
                                              int E, int N, int G)
{
    extern __shared__ float lds[];  // [G][5]
    for (int i = threadIdx.x; i < 5 * G; i += blockDim.x) lds[i] = 0.f;
    __syncthreads();

    int gt = blockIdx.x * blockDim.x + threadIdx.x;
    int TT = gridDim.x * blockDim.x;

    for (int e = gt; e < E; e += TT) {
        int b = batch[dst[e]];
        float w = ew[e];
        const float* zp = &z[(size_t)src[e] * 4];
        atomicAdd(&lds[b * 5 + 0], w * zp[0]);
        atomicAdd(&lds[b * 5 + 1], w * zp[1]);
    }
    for (int n = gt; n < N; n += TT) {
        int b = batch[n];
        const float* zp = &z[(size_t)n * 4];
        atomicAdd(&lds[b * 5 + 2], zp[2]);
        atomicAdd(&lds[b * 5 + 3], zp[3]);
        atomicAdd(&lds[b * 5 + 4], 1.0f);
    }
    __syncthreads();
    for (int i = threadIdx.x; i < 5 * G; i += blockDim.x) {
        float v = lds[i];
        if (v != 0.f) atomicAdd(&gacc[i], v);
    }
}

// out[g][c] = (edge_acc + node_acc + cnt*b3W[c]) / max(cnt,1) + b_lin[c]
__global__ void k_final(const float* __restrict__ gacc, const float* __restrict__ b3W,
                        const float* __restrict__ b_lin, float* __restrict__ out, int G)
{
    int t = blockIdx.x * blockDim.x + threadIdx.x;
    if (t < G * 2) {
        int g = t >> 1, c = t & 1;
        float cnt = gacc[g * 5 + 4];
        float s = gacc[g * 5 + c] + gacc[g * 5 + 2 + c] + cnt * b3W[c];
        out[t] = s / fmaxf(cnt, 1.f) + b_lin[c];
    }
}

extern "C" void kernel_launch(void* const* d_in, const int* in_sizes, int n_in,
                              void* d_out, int out_size, void* d_ws, size_t ws_size,
                              hipStream_t stream)
{
    const float* x       = (const float*)d_in[0];
    const int*   ei      = (const int*)  d_in[1];
    const int*   batch   = (const int*)  d_in[2];
    const float* ew      = (const float*)d_in[3];
    const float* W1_rel  = (const float*)d_in[4];
    const float* b1      = (const float*)d_in[5];
    const float* W1_root = (const float*)d_in[6];
    const float* W2_rel  = (const float*)d_in[7];
    const float* b2      = (const float*)d_in[8];
    const float* W2_root = (const float*)d_in[9];
    const float* W3_rel  = (const float*)d_in[10];
    const float* b3      = (const float*)d_in[11];
    const float* W3_root = (const float*)d_in[12];
    const float* W_lin   = (const float*)d_in[13];
    const float* b_lin   = (const float*)d_in[14];
    float* out = (float*)d_out;

    const int N = in_sizes[0];      // x is [N,1]
    const int E = in_sizes[3];      // edge_weight is [E]
    const int G = out_size / 2;
    const int* src = ei;
    const int* dst = ei + E;

    float* ws = (float*)d_ws;
    size_t o = 0;
    float* agg1 = ws + o; o += (size_t)N;           // zeroed
    float* agg2 = ws + o; o += (size_t)N * 64;      // zeroed
    float* gacc = ws + o; o += (size_t)G * 5;       // zeroed
    size_t zero_floats = o;
    float* h1    = ws + o; o += (size_t)N * 64;
    float* z     = ws + o; o += (size_t)N * 4;
    float* Mrel  = ws + o; o += 128;
    float* Mroot = ws + o; o += 128;
    float* b3W   = ws + o; o += 4;
    float* W2relT  = ws + o; o += 4096;
    float* W2rootT = ws + o; o += 4096;

    hipMemsetAsync(d_ws, 0, zero_floats * sizeof(float), stream);

    hipLaunchKernelGGL(k_small, dim3(1), dim3(256), 0, stream,
                       W3_rel, b3, W3_root, W_lin, W2_rel, W2_root,
                       Mrel, Mroot, b3W, W2relT, W2rootT);

    hipLaunchKernelGGL(k_edge1, dim3((E + 255) / 256), dim3(256), 0, stream,
                       src, dst, ew, x, agg1, E);

    hipLaunchKernelGGL(k_node1, dim3((N * 16 + 255) / 256), dim3(256), 0, stream,
                       x, agg1, W1_rel, b1, W1_root, h1, N);

    hipLaunchKernelGGL(k_edge2, dim3((E * 16 + 255) / 256), dim3(256), 0, stream,
                       src, dst, ew, h1, agg2, E);

    hipLaunchKernelGGL(k_node2, dim3((N + 63) / 64), dim3(256), 0, stream,
                       agg2, h1, W2relT, b2, W2rootT, Mrel, Mroot, z, N);

    hipLaunchKernelGGL(k_pool, dim3(1024), dim3(256), 5 * G * sizeof(float), stream,
                       src, dst, ew, batch, z, gacc, E, N, G);

    hipLaunchKernelGGL(k_final, dim3((G * 2 + 255) / 256), dim3(256), 0, stream,
                       gacc, b3W, b_lin, out, G);
}

// Round 2
// 369.280 us; speedup vs baseline: 3.2794x; 3.2794x over previous
//
#include <hip/hip_runtime.h>

// ---------------------------------------------------------------------------
// GNN: 3x GraphConv(H=64) + global_mean_pool + Linear(64->2)
// N=100000, E=1200000, G=256, C_IN=1, C_OUT=2
//
// Round-2 structure: build CSR by dst on-device, turn all edge passes into
// gathers (no f32 atomics). Layer-1 is rank-1 (C_IN=1) so h1 is recomputed
// on the fly from {agg1,x} (8B/node) instead of materialized (256B/node).
// Layer-3 + pool + head fold into a per-node 4-vector z.
// ---------------------------------------------------------------------------

static __device__ __forceinline__ float4 ld4(const float* p) {
    return *reinterpret_cast<const float4*>(p);
}

// Precompute: Mrel = W3_rel@W_lin, Mroot = W3_root@W_lin, b3W = b3@W_lin,
// plus W2 transposes for the GEMM kernel.
__global__ void k_small(const float* __restrict__ W3_rel, const float* __restrict__ b3,
                        const float* __restrict__ W3_root, const float* __restrict__ W_lin,
                        const float* __restrict__ W2_rel, const float* __restrict__ W2_root,
                        float* __restrict__ Mrel, float* __restrict__ Mroot,
                        float* __restrict__ b3W,
                        float* __restrict__ W2relT, float* __restrict__ W2rootT)
{
    int t = threadIdx.x;
    for (int i = t; i < 4096; i += 256) {
        int k = i >> 6, j = i & 63;
        W2relT[j * 64 + k]  = W2_rel[i];
        W2rootT[j * 64 + k] = W2_root[i];
    }
    if (t < 128) {
        int i = t >> 1, c = t & 1;
        float sr = 0.f, so = 0.f;
        for (int k = 0; k < 64; ++k) {
            float wl = W_lin[k * 2 + c];
            sr += W3_rel[i * 64 + k] * wl;
            so += W3_root[i * 64 + k] * wl;
        }
        Mrel[t]  = sr;
        Mroot[t] = so;
    }
    if (t < 2) {
        float s = 0.f;
        for (int k = 0; k < 64; ++k) s += b3[k] * W_lin[k * 2 + t];
        b3W[t] = s;
    }
}

// ---- CSR build -------------------------------------------------------------
__global__ __launch_bounds__(256) void k_hist(const int* __restrict__ dst,
                                              int* __restrict__ deg, int E)
{
    int e = blockIdx.x * 256 + threadIdx.x;
    if (e < E) atomicAdd(&deg[dst[e]], 1);
}

__global__ __launch_bounds__(256) void k_blocksum(const int* __restrict__ deg,
                                                  int* __restrict__ bsum, int N)
{
    __shared__ int s[256];
    int i = blockIdx.x * 256 + threadIdx.x;
    s[threadIdx.x] = (i < N) ? deg[i] : 0;
    __syncthreads();
    for (int o = 128; o > 0; o >>= 1) {
        if (threadIdx.x < o) s[threadIdx.x] += s[threadIdx.x + o];
        __syncthreads();
    }
    if (threadIdx.x == 0) bsum[blockIdx.x] = s[0];
}

__global__ __launch_bounds__(256) void k_scanbsum(const int* __restrict__ bsum,
                                                  int* __restrict__ bpref, int nb)
{
    __shared__ int s[256];
    __shared__ int carry;
    if (threadIdx.x == 0) carry = 0;
    __syncthreads();
    for (int base = 0; base < nb; base += 256) {
        int i = base + threadIdx.x;
        int v = (i < nb) ? bsum[i] : 0;
        s[threadIdx.x] = v;
        __syncthreads();
        for (int off = 1; off < 256; off <<= 1) {
            int t = (threadIdx.x >= off) ? s[threadIdx.x - off] : 0;
            __syncthreads();
            s[threadIdx.x] += t;
            __syncthreads();
        }
        if (i < nb) bpref[i] = carry + s[threadIdx.x] - v;  // exclusive
        __syncthreads();
        if (threadIdx.x == 0) carry += s[255];
        __syncthreads();
    }
}

__global__ __launch_bounds__(256) void k_scan3(const int* __restrict__ deg,
                                               const int* __restrict__ bpref,
                                               int* __restrict__ rowptr, int N, int E)
{
    __shared__ int s[256];
    int i = blockIdx.x * 256 + threadIdx.x;
    int v = (i < N) ? deg[i] : 0;
    s[threadIdx.x] = v;
    __syncthreads();
    for (int off = 1; off < 256; off <<= 1) {
        int t = (threadIdx.x >= off) ? s[threadIdx.x - off] : 0;
        __syncthreads();
        s[threadIdx.x] += t;
        __syncthreads();
    }
    if (i < N) rowptr[i] = bpref[blockIdx.x] + s[threadIdx.x] - v;
    if (blockIdx.x == 0 && threadIdx.x == 0) rowptr[N] = E;
}

__global__ __launch_bounds__(256) void k_scatter(const int* __restrict__ src,
                                                 const int* __restrict__ dst,
                                                 const float* __restrict__ ew,
                                                 const int* __restrict__ rowptr,
                                                 int* __restrict__ cursor,
                                                 int2* __restrict__ csr, int E)
{
    int e = blockIdx.x * 256 + threadIdx.x;
    if (e < E) {
        int d = dst[e];
        int pos = rowptr[d] + atomicAdd(&cursor[d], 1);
        int2 v;
        v.x = src[e];
        v.y = __float_as_int(ew[e]);
        csr[pos] = v;
    }
}

// ---- layer 1: agg1[n] = sum ew*x[src]; pack axn = {agg1, x} ---------------
__global__ __launch_bounds__(256) void k_agg1(const int2* __restrict__ csr,
                                              const int* __restrict__ rowptr,
                                              const float* __restrict__ x,
                                              float2* __restrict__ axn, int N)
{
    int n = blockIdx.x * 256 + threadIdx.x;
    if (n >= N) return;
    int b = rowptr[n], en = rowptr[n + 1];
    float a = 0.f;
    for (int e = b; e < en; ++e) {
        int2 sw = csr[e];
        a = fmaf(__int_as_float(sw.y), x[sw.x], a);
    }
    axn[n] = make_float2(a, x[n]);
}

// ---- layer 2 aggregation (the heavy pass, now atomic-free) -----------------
// One wave per node, lane = channel. h1[src] recomputed from axn[src] (8B).
__global__ __launch_bounds__(256) void k_agg2(const int2* __restrict__ csr,
                                              const int* __restrict__ rowptr,
                                              const float2* __restrict__ axn,
                                              const float* __restrict__ W1_rel,
                                              const float* __restrict__ b1,
                                              const float* __restrict__ W1_root,
                                              float* __restrict__ agg2, int N)
{
    int n = (blockIdx.x * 256 + threadIdx.x) >> 6;
    int lane = threadIdx.x & 63;
    if (n >= N) return;
    float wrel = W1_rel[lane], wroot = W1_root[lane], bj = b1[lane];
    int b = rowptr[n], en = rowptr[n + 1];
    float acc = 0.f;
    for (int e = b; e < en; ++e) {
        int2 sw = csr[e];
        float w = __int_as_float(sw.y);
        float2 ax = axn[sw.x];
        float h = fmaxf(fmaf(ax.x, wrel, fmaf(ax.y, wroot, bj)), 0.f);
        acc = fmaf(w, h, acc);
    }
    agg2[(size_t)n * 64 + lane] = acc;
}

// ---- layer-2 node GEMM fused with layer-3 fold -----------------------------
// h2 = relu(agg2@W2_rel + h1@W2_root + b2) in registers; z = [h2@Mrel, h2@Mroot]
__global__ __launch_bounds__(256) void k_node2(const float* __restrict__ agg2,
                                               const float2* __restrict__ axn,
                                               const float* __restrict__ W2relT,
                                               const float* __restrict__ b2,
                                               const float* __restrict__ W2rootT,
                                               const float* __restrict__ W1_rel,
                                               const float* __restrict__ b1,
                                               const float* __restrict__ W1_root,
                                               const float* __restrict__ Mrel,
                                               const float* __restrict__ Mroot,
                                               float* __restrict__ z, int N)
{
    __shared__ float A2[64][68];
    __shared__ float H1[64][68];
    __shared__ float WR1[64], WO1[64], B1s[64], BB[64];
    __shared__ float MC[64][4];

    const int t = threadIdx.x;
    if (t < 64) {
        WR1[t] = W1_rel[t];
        WO1[t] = W1_root[t];
        B1s[t] = b1[t];
        BB[t]  = b2[t];
    }
    if (t < 128) {
        int j = t >> 1, c = t & 1;
        MC[j][c]     = Mrel[t];
        MC[j][c + 2] = Mroot[t];
    }
    __syncthreads();

    const int n0 = blockIdx.x * 64;
    for (int i = t; i < 1024; i += 256) {
        int r = i >> 4, q = (i & 15) << 2;
        int n = n0 + r;
        float4 a = make_float4(0.f, 0.f, 0.f, 0.f);
        float4 h = a;
        if (n < N) {
            a = ld4(&agg2[(size_t)n * 64 + q]);
            float2 ax = axn[n];
            h.x = fmaxf(fmaf(ax.x, WR1[q + 0], fmaf(ax.y, WO1[q + 0], B1s[q + 0])), 0.f);
            h.y = fmaxf(fmaf(ax.x, WR1[q + 1], fmaf(ax.y, WO1[q + 1], B1s[q + 1])), 0.f);
            h.z = fmaxf(fmaf(ax.x, WR1[q + 2], fmaf(ax.y, WO1[q + 2], B1s[q + 2])), 0.f);
            h.w = fmaxf(fmaf(ax.x, WR1[q + 3], fmaf(ax.y, WO1[q + 3], B1s[q + 3])), 0.f);
        }
        *reinterpret_cast<float4*>(&A2[r][q]) = a;
        *reinterpret_cast<float4*>(&H1[r][q]) = h;
    }
    __syncthreads();

    const int ng = t >> 4, jg = t & 15;
    const int rn = ng << 2;
    const int jb = jg << 2;

    float acc[4][4];
#pragma unroll
    for (int i = 0; i < 4; ++i)
#pragma unroll
        for (int j = 0; j < 4; ++j) acc[i][j] = 0.f;

    for (int k = 0; k < 64; k += 4) {
        float4 av[4], hv[4], wv[4], ov[4];
#pragma unroll
        for (int i = 0; i < 4; ++i) {
            av[i] = *reinterpret_cast<float4*>(&A2[rn + i][k]);
            hv[i] = *reinterpret_cast<float4*>(&H1[rn + i][k]);
        }
#pragma unroll
        for (int j = 0; j < 4; ++j) {
            wv[j] = ld4(&W2relT[(jb + j) * 64 + k]);
            ov[j] = ld4(&W2rootT[(jb + j) * 64 + k]);
        }
#pragma unroll
        for (int i = 0; i < 4; ++i)
#pragma unroll
            for (int j = 0; j < 4; ++j) {
                acc[i][j] += av[i].x * wv[j].x + av[i].y * wv[j].y +
                             av[i].z * wv[j].z + av[i].w * wv[j].w +
                             hv[i].x * ov[j].x + hv[i].y * ov[j].y +
                             hv[i].z * ov[j].z + hv[i].w * ov[j].w;
            }
    }

    float4 p[4];
#pragma unroll
    for (int i = 0; i < 4; ++i) {
        float z0 = 0.f, z1 = 0.f, z2 = 0.f, z3 = 0.f;
#pragma unroll
        for (int j = 0; j < 4; ++j) {
            float h2 = fmaxf(acc[i][j] + BB[jb + j], 0.f);
            z0 += h2 * MC[jb + j][0];
            z1 += h2 * MC[jb + j][1];
            z2 += h2 * MC[jb + j][2];
            z3 += h2 * MC[jb + j][3];
        }
        p[i] = make_float4(z0, z1, z2, z3);
    }
#pragma unroll
    for (int m = 1; m < 16; m <<= 1) {
#pragma unroll
        for (int i = 0; i < 4; ++i) {
            p[i].x += __shfl_xor(p[i].x, m);
            p[i].y += __shfl_xor(p[i].y, m);
            p[i].z += __shfl_xor(p[i].z, m);
            p[i].w += __shfl_xor(p[i].w, m);
        }
    }
    if (jg == 0) {
#pragma unroll
        for (int i = 0; i < 4; ++i) {
            int n = n0 + rn + i;
            if (n < N) *reinterpret_cast<float4*>(&z[(size_t)n * 4]) = p[i];
        }
    }
}

// ---- pool: per-node CSR gather of edge term + node term, LDS-binned --------
__global__ __launch_bounds__(256) void k_pool(const int2* __restrict__ csr,
                                              const int* __restrict__ rowptr,
                                              const int* __restrict__ batch,
                                              const float* __restrict__ z4,
                                              float* __restrict__ gacc, int N, int G)
{
    extern __shared__ float lds[];  // [G][5]
    for (int i = threadIdx.x; i < 5 * G; i += 256) lds[i] = 0.f;
    __syncthreads();

    int gt = blockIdx.x * 256 + threadIdx.x;
    int TT = gridDim.x * 256;
    for (int n = gt; n < N; n += TT) {
        int bg = batch[n];
        int b = rowptr[n], en = rowptr[n + 1];
        float s0 = 0.f, s1 = 0.f;
        for (int e = b; e < en; ++e) {
            int2 sw = csr[e];
            float w = __int_as_float(sw.y);
            float2 zz = *reinterpret_cast<const float2*>(&z4[(size_t)sw.x * 4]);
            s0 = fmaf(w, zz.x, s0);
            s1 = fmaf(w, zz.y, s1);
        }
        float2 zw = *reinterpret_cast<const float2*>(&z4[(size_t)n * 4 + 2]);
        atomicAdd(&lds[bg * 5 + 0], s0);
        atomicAdd(&lds[bg * 5 + 1], s1);
        atomicAdd(&lds[bg * 5 + 2], zw.x);
        atomicAdd(&lds[bg * 5 + 3], zw.y);
        atomicAdd(&lds[bg * 5 + 4], 1.0f);
    }
    __syncthreads();
    for (int i = threadIdx.x; i < 5 * G; i += 256) {
        float v = lds[i];
        if (v != 0.f) atomicAdd(&gacc[i], v);
    }
}

__global__ void k_final(const float* __restrict__ gacc, const float* __restrict__ b3W,
                        const float* __restrict__ b_lin, float* __restrict__ out, int G)
{
    int t = blockIdx.x * blockDim.x + threadIdx.x;
    if (t < G * 2) {
        int g = t >> 1, c = t & 1;
        float cnt = gacc[g * 5 + 4];
        float s = gacc[g * 5 + c] + gacc[g * 5 + 2 + c] + cnt * b3W[c];
        out[t] = s / fmaxf(cnt, 1.f) + b_lin[c];
    }
}

extern "C" void kernel_launch(void* const* d_in, const int* in_sizes, int n_in,
                              void* d_out, int out_size, void* d_ws, size_t ws_size,
                              hipStream_t stream)
{
    const float* x       = (const float*)d_in[0];
    const int*   ei      = (const int*)  d_in[1];
    const int*   batch   = (const int*)  d_in[2];
    const float* ew      = (const float*)d_in[3];
    const float* W1_rel  = (const float*)d_in[4];
    const float* b1      = (const float*)d_in[5];
    const float* W1_root = (const float*)d_in[6];
    const float* W2_rel  = (const float*)d_in[7];
    const float* b2      = (const float*)d_in[8];
    const float* W2_root = (const float*)d_in[9];
    const float* W3_rel  = (const float*)d_in[10];
    const float* b3      = (const float*)d_in[11];
    const float* W3_root = (const float*)d_in[12];
    const float* W_lin   = (const float*)d_in[13];
    const float* b_lin   = (const float*)d_in[14];
    float* out = (float*)d_out;

    const int N = in_sizes[0];
    const int E = in_sizes[3];
    const int G = out_size / 2;
    const int NB = (N + 255) / 256;
    const int* src = ei;
    const int* dst = ei + E;

    char* wsb = (char*)d_ws;
    size_t o = 0;
    auto take = [&](size_t bytes) -> char* {
        char* p = wsb + o;
        o += (bytes + 15) & ~(size_t)15;
        return p;
    };
    int*    deg    = (int*)   take((size_t)N * 4);
    int*    cursor = (int*)   take((size_t)N * 4);
    float*  gacc   = (float*) take((size_t)G * 5 * 4);
    size_t  zero_bytes = o;
    int*    rowptr = (int*)   take((size_t)(N + 1) * 4);
    int*    bsum   = (int*)   take((size_t)NB * 4);
    int*    bpref  = (int*)   take((size_t)NB * 4);
    int2*   csr    = (int2*)  take((size_t)E * 8);
    float2* axn    = (float2*)take((size_t)N * 8);
    float*  agg2   = (float*) take((size_t)N * 64 * 4);
    float*  z      = (float*) take((size_t)N * 4 * 4);
    float*  Mrel   = (float*) take(128 * 4);
    float*  Mroot  = (float*) take(128 * 4);
    float*  b3W    = (float*) take(4 * 4);
    float*  W2relT  = (float*)take(4096 * 4);
    float*  W2rootT = (float*)take(4096 * 4);

    hipMemsetAsync(d_ws, 0, zero_bytes, stream);

    hipLaunchKernelGGL(k_small, dim3(1), dim3(256), 0, stream,
                       W3_rel, b3, W3_root, W_lin, W2_rel, W2_root,
                       Mrel, Mroot, b3W, W2relT, W2rootT);

    hipLaunchKernelGGL(k_hist, dim3((E + 255) / 256), dim3(256), 0, stream, dst, deg, E);
    hipLaunchKernelGGL(k_blocksum, dim3(NB), dim3(256), 0, stream, deg, bsum, N);
    hipLaunchKernelGGL(k_scanbsum, dim3(1), dim3(256), 0, stream, bsum, bpref, NB);
    hipLaunchKernelGGL(k_scan3, dim3(NB), dim3(256), 0, stream, deg, bpref, rowptr, N, E);
    hipLaunchKernelGGL(k_scatter, dim3((E + 255) / 256), dim3(256), 0, stream,
                       src, dst, ew, rowptr, cursor, csr, E);

    hipLaunchKernelGGL(k_agg1, dim3(NB), dim3(256), 0, stream, csr, rowptr, x, axn, N);

    hipLaunchKernelGGL(k_agg2, dim3((N * 64 + 255) / 256), dim3(256), 0, stream,
                       csr, rowptr, axn, W1_rel, b1, W1_root, agg2, N);

    hipLaunchKernelGGL(k_node2, dim3((N + 63) / 64), dim3(256), 0, stream,
                       agg2, axn, W2relT, b2, W2rootT, W1_rel, b1, W1_root,
                       Mrel, Mroot, z, N);

    hipLaunchKernelGGL(k_pool, dim3(512), dim3(256), 5 * G * sizeof(float), stream,
                       csr, rowptr, batch, z, gacc, N, G);

    hipLaunchKernelGGL(k_final, dim3((G * 2 + 255) / 256), dim3(256), 0, stream,
                       gacc, b3W, b_lin, out, G);
}